// Round 18
// baseline (54.761 us; speedup 1.0000x reference)
//
#include <hip/hip_runtime.h>
#include <hip/hip_bf16.h>
#include <math.h>

// Trittention forward: B=2,H=8,S=192,D=64, fp32 in/out.
// scores[q,t,s] = sum_h q[h]*k1[t,h]*k2[s,h]  ==  (W @ k2^T), W = q (.) k1
// softmax over flat (t,s); z = (sum_t At v1 + sum_s As v2)/suma via marginals.
// Round 18: persistent head-grouped blocks. Grid = 512 (exactly 2/CU);
// block owns head b>>5, processes 3 q-pairs. k2 DMA + bfr hoist ONCE per
// block (head-invariant, was 3x); W-staging of pair n+1 overlapped with
// pair n's epilogue (disjoint LDS: wl writes vs red/v1/v2 reads);
// k1/v1/v2 L1-hot across pairs. Inner loop identical to r17 (52.7us) ->
// absmax must stay exactly 0.2695312. Spill sentinel: WRITE_SIZE.

#define SS 192
#define DD 64
#define NT 512   // 8 waves: 2 (t) x 4 (s) wave grid, wave tile 96x48

typedef __attribute__((ext_vector_type(8))) short bf16x8;
typedef __attribute__((ext_vector_type(4))) float f32x4;

static __device__ __forceinline__ unsigned pk_bf16(float a, float b) {
    union { __hip_bfloat162 h; unsigned u; } cv;
    cv.h = __float22bfloat162_rn(float2{a, b});   // v_cvt_pk_bf16_f32 (RNE)
    return cv.u;
}

// one DPP-add step: v += v[lane ^pattern], within rows of 16 lanes
#define DPP_STEP(v, CTRL)                                                   \
    (v) += __int_as_float(__builtin_amdgcn_update_dpp(                      \
        0, __float_as_int(v), (CTRL), 0xF, 0xF, true))

static __device__ __forceinline__ float row16_sum(float v) {
    DPP_STEP(v, 0xB1);   // quad_perm [1,0,3,2]  : xor 1
    DPP_STEP(v, 0x4E);   // quad_perm [2,3,0,1]  : xor 2
    DPP_STEP(v, 0x141);  // row_half_mirror
    DPP_STEP(v, 0x140);  // row_mirror
    return v;            // all 16 lanes of the row hold the row sum
}

// ---- prepack: k2 fp32 -> bf16, stored PRE-SWIZZLED (chunk c at c^(r&7)) ----
__global__ __launch_bounds__(512) void k2_pack(const float* __restrict__ k2g,
                                               uint4* __restrict__ outp) {
    int i = blockIdx.x * 512 + threadIdx.x;   // 16B-chunk id, 0..24575
    const float4* in = (const float4*)k2g;
    float4 a = in[2 * i], b = in[2 * i + 1];
    uint4 w;
    w.x = pk_bf16(a.x, a.y);
    w.y = pk_bf16(a.z, a.w);
    w.z = pk_bf16(b.x, b.y);
    w.w = pk_bf16(b.z, b.w);
    int ih = i & 1535;                        // within-head chunk
    int r = ih >> 3, c = ih & 7;
    outp[(i & ~1535) | (r * 8 + (c ^ (r & 7)))] = w;
}

#define AT(qq, t) red[(qq) * SS + (t)]
#define AS(qq, s) red[2 * SS + (qq) * SS + (s)]
#define ZSH(qq, d) red[4 * SS + (qq) * DD + (d)]

// stage W = q*k1*log2e for a q-pair into wl[0..1] (bf16, swizzled)
static __device__ __forceinline__ void stage_w(const float4* __restrict__ k1v,
                                               const float* __restrict__ qg,
                                               int q0, int tid,
                                               uint4 (* __restrict__ wl)[SS * 8]) {
    const float L2E = 1.44269504088896340736f;
    const float4* qv0 = (const float4*)(qg + (size_t)q0 * DD);
    const int c = tid & 7;                // chunk within row: constant/thread
    float4 p00 = qv0[2 * c], p01 = qv0[2 * c + 1];
    float4 p10 = qv0[16 + 2 * c], p11 = qv0[16 + 2 * c + 1];  // q0+1 row
    p00.x *= L2E; p00.y *= L2E; p00.z *= L2E; p00.w *= L2E;
    p01.x *= L2E; p01.y *= L2E; p01.z *= L2E; p01.w *= L2E;
    p10.x *= L2E; p10.y *= L2E; p10.z *= L2E; p10.w *= L2E;
    p11.x *= L2E; p11.y *= L2E; p11.z *= L2E; p11.w *= L2E;
    #pragma unroll 1
    for (int it = 0; it < (SS * 8) / NT; ++it) {   // 3 serial iters
        int f8 = tid + it * NT;            // 16B-chunk id
        int r = f8 >> 3;
        int idx = r * 8 + (c ^ (r & 7));
        float4 a0 = k1v[2 * f8], a1 = k1v[2 * f8 + 1];
        uint4 w;
        w.x = pk_bf16(a0.x * p00.x, a0.y * p00.y);
        w.y = pk_bf16(a0.z * p00.z, a0.w * p00.w);
        w.z = pk_bf16(a1.x * p01.x, a1.y * p01.y);
        w.w = pk_bf16(a1.z * p01.z, a1.w * p01.w);
        wl[0][idx] = w;
        w.x = pk_bf16(a0.x * p10.x, a0.y * p10.y);
        w.y = pk_bf16(a0.z * p10.z, a0.w * p10.w);
        w.z = pk_bf16(a1.x * p11.x, a1.y * p11.y);
        w.w = pk_bf16(a1.z * p11.z, a1.w * p11.w);
        wl[1][idx] = w;
    }
}

__launch_bounds__(NT, 4)
__global__ void tritt_fwd(const float* __restrict__ qg,
                          const float* __restrict__ k1g,
                          const uint4* __restrict__ k2p,   // bf16, pre-swizzled
                          const float* __restrict__ v1g,
                          const float* __restrict__ v2g,
                          float* __restrict__ zg,
                          float* __restrict__ lseg) {
    // bf16 tiles, row = 64 bf16 = 8 chunks of 16B; chunk c stored at c^(r&7).
    __shared__ uint4 k2l[SS * 8];
    __shared__ uint4 wl[2][SS * 8];
    __shared__ float red[4 * SS + 2 * DD];    // At[2],As[2],zsh[2]

    const int tid = threadIdx.x;
    const int bid = blockIdx.x;           // 512 blocks: 32 per head
    const int head = bid >> 5;
    const int pbase = (bid & 31) * 3;     // first q-pair index in head
    const size_t hb = (size_t)head * SS * DD;

    // k2 staging ONCE per block (head-invariant): global->LDS DMA
    const uint4* k2h = k2p + (size_t)head * (SS * 8);
    #pragma unroll
    for (int it = 0; it < (SS * 8) / NT; ++it) {   // 3 iters
        int f8 = tid + it * NT;
        __builtin_amdgcn_global_load_lds(
            (const __attribute__((address_space(1))) unsigned int*)(k2h + f8),
            (__attribute__((address_space(3))) unsigned int*)&k2l[f8],
            16, 0, 0);
    }

    red[tid] = 0.f;
    if (tid < 4 * SS + 2 * DD - NT) red[tid + NT] = 0.f;

    const float4* k1v = (const float4*)(k1g + hb);
    stage_w(k1v, qg, head * SS + 2 * pbase, tid, wl);
    __syncthreads();   // B1: DMA drained, wl(pair 0) ready, red zeroed

    const int lane = tid & 63;
    const int wid  = tid >> 6;
    const int wt   = wid >> 2;            // 0..1
    const int ws   = wid & 3;             // 0..3
    const int lrow = lane & 15;
    const int lk   = lane >> 4;           // 0..3 (k-group)
    const int lrm  = lrow & 7;
    const int sw0 = lk ^ lrm;             // ks = 0
    const int sw1 = (4 + lk) ^ lrm;       // ks = 1
    const int ab  = (wt * 96 + lrow) * 8; // A chunk base
    const int bb  = (ws * 48 + lrow) * 8; // B chunk base

    // B-fragments hoisted ONCE per block (k2 head-invariant).
    bf16x8 bfr[2][3];
    #pragma unroll
    for (int j = 0; j < 3; ++j) {
        bfr[0][j] = *(const bf16x8*)&k2l[bb + j * 128 + sw0];
        bfr[1][j] = *(const bf16x8*)&k2l[bb + j * 128 + sw1];
    }

    const int d = tid & 63;
    const int g = tid >> 6;               // 0..7, each covers 24 rows
    const float* v1p = v1g + hb;
    const float* v2p = v2g + hb;

    #pragma unroll 1
    for (int n = 0; n < 3; ++n) {
        const int q0 = head * SS + 2 * (pbase + n);

        // ---- fused score-GEMM + exp + marginals (both q's) ----
        #pragma unroll 1
        for (int qq = 0; qq < 2; ++qq) {
            const uint4* wlq = wl[qq];
            f32x4 cv[3];                  // per-column partials (vector)
            #pragma unroll
            for (int j = 0; j < 3; ++j) cv[j] = (f32x4){0.f, 0.f, 0.f, 0.f};
            #pragma unroll
            for (int i = 0; i < 6; ++i) {
                f32x4 acc[3];
                #pragma unroll
                for (int j = 0; j < 3; ++j) acc[j] = (f32x4){0.f, 0.f, 0.f, 0.f};
                {   // ks = 0
                    bf16x8 afr = *(const bf16x8*)&wlq[ab + i * 128 + sw0];
                    #pragma unroll
                    for (int j = 0; j < 3; ++j)
                        acc[j] = __builtin_amdgcn_mfma_f32_16x16x32_bf16(
                            afr, bfr[0][j], acc[j], 0, 0, 0);
                }
                {   // ks = 1
                    bf16x8 afr = *(const bf16x8*)&wlq[ab + i * 128 + sw1];
                    #pragma unroll
                    for (int j = 0; j < 3; ++j)
                        acc[j] = __builtin_amdgcn_mfma_f32_16x16x32_bf16(
                            afr, bfr[1][j], acc[j], 0, 0, 0);
                }
                // D mapping: col(s) = lane&15, row(t) = (lane>>4)*4 + reg.
                f32x4 rsv = (f32x4){0.f, 0.f, 0.f, 0.f};
                #pragma unroll
                for (int j = 0; j < 3; ++j) {
                    f32x4 pv;
                    #pragma unroll
                    for (int r = 0; r < 4; ++r)
                        pv[r] = __builtin_amdgcn_exp2f(acc[j][r]);
                    rsv += pv;            // 4 independent lanes (pk adds)
                    cv[j] += pv;
                }
                #pragma unroll
                for (int r = 0; r < 4; ++r) {
                    float v = row16_sum(rsv[r]);   // DPP, all-VALU
                    if (lrow == 0)
                        atomicAdd(&AT(qq, wt * 96 + i * 16 + lk * 4 + r), v);
                }
            }
            #pragma unroll
            for (int j = 0; j < 3; ++j) {
                float v = (cv[j][0] + cv[j][1]) + (cv[j][2] + cv[j][3]);
                v += __shfl_xor(v, 16, 64);
                v += __shfl_xor(v, 32, 64);
                if (lane < 16)
                    atomicAdd(&AS(qq, ws * 48 + j * 16 + lane), v);
            }
        }
        __syncthreads();   // B2: marginals complete; wl free to restage

        // ---- sumas (redundant per-wave reduce) ----
        float suma0 = AT(0, lane) + AT(0, lane + 64) + AT(0, lane + 128);
        suma0 = row16_sum(suma0);
        suma0 += __shfl_xor(suma0, 16, 64);
        suma0 += __shfl_xor(suma0, 32, 64);
        float suma1 = AT(1, lane) + AT(1, lane + 64) + AT(1, lane + 128);
        suma1 = row16_sum(suma1);
        suma1 += __shfl_xor(suma1, 16, 64);
        suma1 += __shfl_xor(suma1, 32, 64);

        // ---- epilogue (reads red/v1/v2)  ∥  stage W for pair n+1 (wl) ----
        float zp0 = 0.f, zp1 = 0.f;
        #pragma unroll 1
        for (int rb = 0; rb < 24; rb += 4) {
            int t0 = g * 24 + rb;
            float4 at0 = *(const float4*)&AT(0, t0);
            float4 as0 = *(const float4*)&AS(0, t0);
            float4 at1 = *(const float4*)&AT(1, t0);
            float4 as1 = *(const float4*)&AS(1, t0);
            #pragma unroll
            for (int r2 = 0; r2 < 4; ++r2) {
                int t = t0 + r2;
                float x1 = v1p[t * DD + d];
                float x2 = v2p[t * DD + d];
                float a0 = (r2 == 0) ? at0.x : (r2 == 1) ? at0.y : (r2 == 2) ? at0.z : at0.w;
                float s0 = (r2 == 0) ? as0.x : (r2 == 1) ? as0.y : (r2 == 2) ? as0.z : as0.w;
                float a1 = (r2 == 0) ? at1.x : (r2 == 1) ? at1.y : (r2 == 2) ? at1.z : at1.w;
                float s1 = (r2 == 0) ? as1.x : (r2 == 1) ? as1.y : (r2 == 2) ? as1.z : as1.w;
                zp0 = fmaf(a0, x1, fmaf(s0, x2, zp0));
                zp1 = fmaf(a1, x1, fmaf(s1, x2, zp1));
            }
        }
        atomicAdd(&ZSH(0, d), zp0);
        atomicAdd(&ZSH(1, d), zp1);

        if (n < 2)
            stage_w(k1v, qg, head * SS + 2 * (pbase + n + 1), tid, wl);

        __syncthreads();   // B3: zsh complete + wl(n+1) staged

        // ---- write z/lse; zero red for next pair (ZSH by its reader) ----
        if (tid < DD) {
            zg[(size_t)q0 * DD + tid] = ZSH(0, tid) / suma0;
            ZSH(0, tid) = 0.f;
        } else if (tid < 2 * DD) {
            zg[(size_t)(q0 + 1) * DD + (tid - DD)] = ZSH(1, tid - DD) / suma1;
            ZSH(1, tid - DD) = 0.f;
        }
        if (tid == 0) lseg[q0] = logf(suma0);
        if (tid == 1) lseg[q0 + 1] = logf(suma1);
        red[tid] = 0.f;                   // At0,At1,As0-part
        if (tid < 4 * SS - NT) red[tid + NT] = 0.f;   // rest of As1
        __syncthreads();   // B4: red zeroed, z written
    }
}

extern "C" void kernel_launch(void* const* d_in, const int* in_sizes, int n_in,
                              void* d_out, int out_size, void* d_ws, size_t ws_size,
                              hipStream_t stream) {
    const float* q  = (const float*)d_in[0];
    const float* k1 = (const float*)d_in[1];
    const float* k2 = (const float*)d_in[2];
    const float* v1 = (const float*)d_in[3];
    const float* v2 = (const float*)d_in[4];
    float* out = (float*)d_out;

    const int nq = in_sizes[0] / DD;      // B*H*S = 3072
    const int nheads = nq / SS;           // 16
    float* zout   = out;
    float* lseout = out + (size_t)nq * DD;
    uint4* k2pack = (uint4*)d_ws;         // nheads*192*64 bf16 = 384 KiB

    // prepack k2 -> bf16 pre-swizzled (q-invariant; deterministic each call)
    int n8 = nheads * SS * DD / 8;        // 24576
    hipLaunchKernelGGL(k2_pack, dim3(n8 / 512), dim3(512), 0, stream, k2, k2pack);

    // persistent: 512 blocks (2/CU), 32 blocks/head x 3 q-pairs each
    hipLaunchKernelGGL(tritt_fwd, dim3(512), dim3(NT), 0, stream,
                       q, k1, (const uint4*)k2pack, v1, v2, zout, lseout);
}

// Round 19
// 51.772 us; speedup vs baseline: 1.0577x; 1.0577x over previous
//
#include <hip/hip_runtime.h>
#include <hip/hip_bf16.h>
#include <math.h>

// Trittention forward: B=2,H=8,S=192,D=64, fp32 in/out.
// scores[q,t,s] = sum_h q[h]*k1[t,h]*k2[s,h]  ==  (W @ k2^T), W = q (.) k1
// softmax over flat (t,s); z = (sum_t At v1 + sum_s As v2)/suma via marginals.
// Round 19: r17 base (best, 52.7us) minus the dead k2l LDS buffer. k2l was
// read exactly once (bfr hoist) then unused; bfr now loads DIRECTLY from the
// prepacked+preswizzled global k2p (same indices, same bits, L2-resident,
// 6x16B one-time per thread). LDS 77.3KB -> 52.7KB -> 3 blocks/CU
// (24 waves, +50% issue capacity; kernel is issue-starved at 16 waves).
// absmax must stay exactly 0.2695312. Spill sentinel: WRITE_SIZE.

#define SS 192
#define DD 64
#define NT 512   // 8 waves: 2 (t) x 4 (s) wave grid, wave tile 96x48

typedef __attribute__((ext_vector_type(8))) short bf16x8;
typedef __attribute__((ext_vector_type(4))) float f32x4;

static __device__ __forceinline__ unsigned pk_bf16(float a, float b) {
    union { __hip_bfloat162 h; unsigned u; } cv;
    cv.h = __float22bfloat162_rn(float2{a, b});   // v_cvt_pk_bf16_f32 (RNE)
    return cv.u;
}

// one DPP-add step: v += v[lane ^pattern], within rows of 16 lanes
#define DPP_STEP(v, CTRL)                                                   \
    (v) += __int_as_float(__builtin_amdgcn_update_dpp(                      \
        0, __float_as_int(v), (CTRL), 0xF, 0xF, true))

static __device__ __forceinline__ float row16_sum(float v) {
    DPP_STEP(v, 0xB1);   // quad_perm [1,0,3,2]  : xor 1
    DPP_STEP(v, 0x4E);   // quad_perm [2,3,0,1]  : xor 2
    DPP_STEP(v, 0x141);  // row_half_mirror
    DPP_STEP(v, 0x140);  // row_mirror
    return v;            // all 16 lanes of the row hold the row sum
}

// ---- prepack: k2 fp32 -> bf16, stored PRE-SWIZZLED (chunk c at c^(r&7)) ----
__global__ __launch_bounds__(512) void k2_pack(const float* __restrict__ k2g,
                                               uint4* __restrict__ outp) {
    int i = blockIdx.x * 512 + threadIdx.x;   // 16B-chunk id, 0..24575
    const float4* in = (const float4*)k2g;
    float4 a = in[2 * i], b = in[2 * i + 1];
    uint4 w;
    w.x = pk_bf16(a.x, a.y);
    w.y = pk_bf16(a.z, a.w);
    w.z = pk_bf16(b.x, b.y);
    w.w = pk_bf16(b.z, b.w);
    int ih = i & 1535;                        // within-head chunk
    int r = ih >> 3, c = ih & 7;
    outp[(i & ~1535) | (r * 8 + (c ^ (r & 7)))] = w;
}

#define AT(qq, t) red[(qq) * SS + (t)]
#define AS(qq, s) red[2 * SS + (qq) * SS + (s)]
#define ZSH(qq, d) red[4 * SS + (qq) * DD + (d)]

__launch_bounds__(NT, 4)
__global__ void tritt_fwd(const float* __restrict__ qg,
                          const float* __restrict__ k1g,
                          const uint4* __restrict__ k2p,   // bf16, pre-swizzled
                          const float* __restrict__ v1g,
                          const float* __restrict__ v2g,
                          float* __restrict__ zg,
                          float* __restrict__ lseg) {
    // W tiles bf16: row = 64 bf16 = 8 chunks of 16B; chunk c at c^(r&7).
    __shared__ uint4 wl[2][SS * 8];           // 49.2 KB
    __shared__ float red[4 * SS + 2 * DD];    // At[2],As[2],zsh[2]: 3.5 KB

    const int tid = threadIdx.x;
    const int q0 = 2 * blockIdx.x;        // global q row; q0,q0+1 same head
    const int head = q0 / SS;
    const size_t hb = (size_t)head * SS * DD;

    red[tid] = 0.f;
    if (tid < 4 * SS + 2 * DD - NT) red[tid + NT] = 0.f;

    // ---- stage W_q = q*k1*log2e for both q's (k1 loaded once) ----
    const float L2E = 1.44269504088896340736f;
    const float4* k1v = (const float4*)(k1g + hb);
    const float4* qv0 = (const float4*)(qg + (size_t)q0 * DD);
    {
        const int c = tid & 7;            // chunk within row: constant/thread
        float4 p00 = qv0[2 * c], p01 = qv0[2 * c + 1];
        float4 p10 = qv0[16 + 2 * c], p11 = qv0[16 + 2 * c + 1]; // q0+1 row
        p00.x *= L2E; p00.y *= L2E; p00.z *= L2E; p00.w *= L2E;
        p01.x *= L2E; p01.y *= L2E; p01.z *= L2E; p01.w *= L2E;
        p10.x *= L2E; p10.y *= L2E; p10.z *= L2E; p10.w *= L2E;
        p11.x *= L2E; p11.y *= L2E; p11.z *= L2E; p11.w *= L2E;
        #pragma unroll 1
        for (int it = 0; it < (SS * 8) / NT; ++it) {   // 3 serial iters
            int f8 = tid + it * NT;        // 16B-chunk id
            int r = f8 >> 3;
            int idx = r * 8 + (c ^ (r & 7));
            float4 a0 = k1v[2 * f8], a1 = k1v[2 * f8 + 1];
            uint4 w;
            w.x = pk_bf16(a0.x * p00.x, a0.y * p00.y);
            w.y = pk_bf16(a0.z * p00.z, a0.w * p00.w);
            w.z = pk_bf16(a1.x * p01.x, a1.y * p01.y);
            w.w = pk_bf16(a1.z * p01.z, a1.w * p01.w);
            wl[0][idx] = w;
            w.x = pk_bf16(a0.x * p10.x, a0.y * p10.y);
            w.y = pk_bf16(a0.z * p10.z, a0.w * p10.w);
            w.z = pk_bf16(a1.x * p11.x, a1.y * p11.y);
            w.w = pk_bf16(a1.z * p11.z, a1.w * p11.w);
            wl[1][idx] = w;
        }
    }

    // ---- fused score-GEMM + exp + marginals. Wave (wt,ws) owns 96x48. ----
    const int lane = tid & 63;
    const int wid  = tid >> 6;
    const int wt   = wid >> 2;            // 0..1
    const int ws   = wid & 3;             // 0..3
    const int lrow = lane & 15;
    const int lk   = lane >> 4;           // 0..3 (k-group)
    const int lrm  = lrow & 7;

    // Swizzle term (ks*4+lk)^lrm is i/j-independent (96,48,16 all ≡0 mod 8).
    const int sw0 = lk ^ lrm;             // ks = 0
    const int sw1 = (4 + lk) ^ lrm;       // ks = 1
    const int ab  = (wt * 96 + lrow) * 8; // A chunk base
    const int bb  = (ws * 48 + lrow) * 8; // B chunk base

    // B-fragments loaded ONCE, DIRECTLY from prepacked global k2p
    // (same indices/bits the k2l LDS copy had; L2-resident, one-time).
    const uint4* k2h = k2p + (size_t)head * (SS * 8);
    bf16x8 bfr[2][3];
    #pragma unroll
    for (int j = 0; j < 3; ++j) {
        bfr[0][j] = *(const bf16x8*)&k2h[bb + j * 128 + sw0];
        bfr[1][j] = *(const bf16x8*)&k2h[bb + j * 128 + sw1];
    }
    __syncthreads();   // wl staged + red zeroed

    #pragma unroll 1
    for (int qq = 0; qq < 2; ++qq) {
        const uint4* wlq = wl[qq];
        f32x4 cv[3];                      // per-column partials (vector)
        #pragma unroll
        for (int j = 0; j < 3; ++j) cv[j] = (f32x4){0.f, 0.f, 0.f, 0.f};
        #pragma unroll
        for (int i = 0; i < 6; ++i) {
            f32x4 acc[3];
            #pragma unroll
            for (int j = 0; j < 3; ++j) acc[j] = (f32x4){0.f, 0.f, 0.f, 0.f};
            {   // ks = 0
                bf16x8 afr = *(const bf16x8*)&wlq[ab + i * 128 + sw0];
                #pragma unroll
                for (int j = 0; j < 3; ++j)
                    acc[j] = __builtin_amdgcn_mfma_f32_16x16x32_bf16(
                        afr, bfr[0][j], acc[j], 0, 0, 0);
            }
            {   // ks = 1
                bf16x8 afr = *(const bf16x8*)&wlq[ab + i * 128 + sw1];
                #pragma unroll
                for (int j = 0; j < 3; ++j)
                    acc[j] = __builtin_amdgcn_mfma_f32_16x16x32_bf16(
                        afr, bfr[1][j], acc[j], 0, 0, 0);
            }
            // D mapping: col(s) = lane&15, row(t) = (lane>>4)*4 + reg.
            f32x4 rsv = (f32x4){0.f, 0.f, 0.f, 0.f};
            #pragma unroll
            for (int j = 0; j < 3; ++j) {
                f32x4 pv;
                #pragma unroll
                for (int r = 0; r < 4; ++r)
                    pv[r] = __builtin_amdgcn_exp2f(acc[j][r]);
                rsv += pv;                // 4 independent lanes (pk adds)
                cv[j] += pv;
            }
            #pragma unroll
            for (int r = 0; r < 4; ++r) {
                float v = row16_sum(rsv[r]);   // DPP, all-VALU
                if (lrow == 0)
                    atomicAdd(&AT(qq, wt * 96 + i * 16 + lk * 4 + r), v);
            }
        }
        #pragma unroll
        for (int j = 0; j < 3; ++j) {
            float v = (cv[j][0] + cv[j][1]) + (cv[j][2] + cv[j][3]);
            v += __shfl_xor(v, 16, 64);
            v += __shfl_xor(v, 32, 64);
            if (lane < 16)
                atomicAdd(&AS(qq, ws * 48 + j * 16 + lane), v);
        }
    }
    __syncthreads();

    // ---- sumas (redundant per-wave reduce; no extra barrier) ----
    float suma0 = AT(0, lane) + AT(0, lane + 64) + AT(0, lane + 128);
    suma0 = row16_sum(suma0);
    suma0 += __shfl_xor(suma0, 16, 64);
    suma0 += __shfl_xor(suma0, 32, 64);
    float suma1 = AT(1, lane) + AT(1, lane + 64) + AT(1, lane + 128);
    suma1 = row16_sum(suma1);
    suma1 += __shfl_xor(suma1, 16, 64);
    suma1 += __shfl_xor(suma1, 32, 64);

    // ---- epilogue: shared v1/v2 loads serve both q's; At/As as float4 ----
    const int d = tid & 63;
    const int g = tid >> 6;               // 0..7, each covers 24 rows
    const float* v1p = v1g + hb;
    const float* v2p = v2g + hb;
    float zp0 = 0.f, zp1 = 0.f;
    #pragma unroll 1
    for (int rb = 0; rb < 24; rb += 4) {
        int t0 = g * 24 + rb;
        float4 at0 = *(const float4*)&AT(0, t0);
        float4 as0 = *(const float4*)&AS(0, t0);
        float4 at1 = *(const float4*)&AT(1, t0);
        float4 as1 = *(const float4*)&AS(1, t0);
        #pragma unroll
        for (int r2 = 0; r2 < 4; ++r2) {
            int t = t0 + r2;
            float x1 = v1p[t * DD + d];
            float x2 = v2p[t * DD + d];
            float a0 = (r2 == 0) ? at0.x : (r2 == 1) ? at0.y : (r2 == 2) ? at0.z : at0.w;
            float s0 = (r2 == 0) ? as0.x : (r2 == 1) ? as0.y : (r2 == 2) ? as0.z : as0.w;
            float a1 = (r2 == 0) ? at1.x : (r2 == 1) ? at1.y : (r2 == 2) ? at1.z : at1.w;
            float s1 = (r2 == 0) ? as1.x : (r2 == 1) ? as1.y : (r2 == 2) ? as1.z : as1.w;
            zp0 = fmaf(a0, x1, fmaf(s0, x2, zp0));
            zp1 = fmaf(a1, x1, fmaf(s1, x2, zp1));
        }
    }
    atomicAdd(&ZSH(0, d), zp0);
    atomicAdd(&ZSH(1, d), zp1);
    __syncthreads();

    if (tid < DD) {
        zg[(size_t)q0 * DD + tid] = ZSH(0, tid) / suma0;
    } else if (tid < 2 * DD) {
        zg[(size_t)(q0 + 1) * DD + (tid - DD)] = ZSH(1, tid - DD) / suma1;
    }
    if (tid == 0) lseg[q0] = logf(suma0);
    if (tid == 1) lseg[q0 + 1] = logf(suma1);
}

extern "C" void kernel_launch(void* const* d_in, const int* in_sizes, int n_in,
                              void* d_out, int out_size, void* d_ws, size_t ws_size,
                              hipStream_t stream) {
    const float* q  = (const float*)d_in[0];
    const float* k1 = (const float*)d_in[1];
    const float* k2 = (const float*)d_in[2];
    const float* v1 = (const float*)d_in[3];
    const float* v2 = (const float*)d_in[4];
    float* out = (float*)d_out;

    const int nq = in_sizes[0] / DD;      // B*H*S = 3072
    const int nheads = nq / SS;           // 16
    float* zout   = out;
    float* lseout = out + (size_t)nq * DD;
    uint4* k2pack = (uint4*)d_ws;         // nheads*192*64 bf16 = 384 KiB

    // prepack k2 -> bf16 pre-swizzled (q-invariant; deterministic each call)
    int n8 = nheads * SS * DD / 8;        // 24576
    hipLaunchKernelGGL(k2_pack, dim3(n8 / 512), dim3(512), 0, stream, k2, k2pack);

    dim3 grid(nq / 2), block(NT);
    hipLaunchKernelGGL(tritt_fwd, grid, block, 0, stream,
                       q, k1, (const uint4*)k2pack, v1, v2, zout, lseout);
}